// Round 1
// baseline (1176.728 us; speedup 1.0000x reference)
//
#include <hip/hip_runtime.h>
#include <math.h>

// ---------------------------------------------------------------------------
// SSHConv3D: steerable spherical-harmonic conv, fused.
// Constants: K=5, MD=3, HH=16, CIN=16, F=32, D=48, NJ=2.
//
// Factorization per voxel p:
//   z[c,j,h] = sum_off atom[off,j,h] * x[c, p+off-2]      (92 active offsets)
//   y[f,h]   = sum_{c,j} w[c,f,j,deg(h)] * z[c,j,h]       (+ central conv at h=0)
//   spec[f,n]= 1/(2n+1) sum_{h in deg n} |y[f,h]|^2  (+ spec_bias)
//   out[fo]  = relu( sum_{f,n} proj_w[fo, f*4+n]*spec[f,n] + proj_b[fo] )
//
// ws layout (floats):
//   [0,     5888)  atab   : float4[16 h][92 e] = {ar_j0, ai_j0, ar_j1, ai_j1}
//   [5888,  9984)  wT     : [n][f][c*2+j]
//   [9984, 14080)  pwT    : [f*4+n][fo]
//   [14080,14112)  out_base[fo] = proj_b + proj_w . spec_bias
//   bytes [56448, 56816) edelta : int[92] LDS-delta per entry
// Entry segments: [0,6)=j0-only (r2=1), [6,26)=both (r2=2,3), [26,92)=j1-only (r2=4,5,6,8)
// ---------------------------------------------------------------------------

#define TZ 4
#define TY 4
#define TX 8
#define LZ 8
#define LY 8
#define LX 12
#define CSTRIDE (LZ*LY*LX)   // 768 floats per channel in LDS

#define ATAB_F   0
#define WT_F     5888
#define PWT_F    9984
#define OB_F     14080
#define EDELTA_B 56448

__global__ __launch_bounds__(256) void ssh_init(
    const float* __restrict__ w, const float* __restrict__ proj_w,
    const float* __restrict__ spec_bias, const float* __restrict__ proj_b,
    float* __restrict__ wsf, int* __restrict__ edelta)
{
    __shared__ float shr[125][16];
    __shared__ float shi[125][16];
    __shared__ float prof[125][2];
    __shared__ float norms[2][16];
    __shared__ int epos[92];
    const int tid = threadIdx.x;
    const float fourpi = 4.0f * 3.14159265358979323846f;

    for (int p = tid; p < 125; p += 256) {
        int d2 = p % 5, d1 = (p / 5) % 5, d0 = p / 25;
        float xc = (float)(d1 - 2), yc = (float)(d0 - 2), zc = (float)(d2 - 2);
        float r2 = xc*xc + yc*yc + zc*zc;
        float r  = sqrtf(r2);
        float phi = atan2f(yc, xc);
        float ct = (r > 0.f) ? (zc / r) : 0.f;
        float st = sqrtf(fmaxf(0.f, 1.f - ct*ct));
        float c1 = cosf(phi), s1 = sinf(phi);
        float c2 = c1*c1 - s1*s1, s2 = 2.f*s1*c1;
        float c3 = c2*c1 - s2*s1, s3 = s2*c1 + c2*s1;
        // Legendre with Condon-Shortley
        float P00 = 1.f;
        float P10 = ct,              P11 = -st;
        float P20 = 0.5f*(3.f*ct*ct - 1.f), P21 = -3.f*ct*st, P22 = 3.f*st*st;
        float P30 = 0.5f*(5.f*ct*ct*ct - 3.f*ct);
        float P31 = -1.5f*(5.f*ct*ct - 1.f)*st;
        float P32 = 15.f*ct*st*st;
        float P33 = -15.f*st*st*st;
        float N00 = sqrtf(1.f/fourpi);
        float N10 = sqrtf(3.f/fourpi);
        float N11 = sqrtf(3.f/fourpi * 0.5f);
        float N20 = sqrtf(5.f/fourpi);
        float N21 = sqrtf(5.f/fourpi / 6.f);
        float N22 = sqrtf(5.f/fourpi / 24.f);
        float N30 = sqrtf(7.f/fourpi);
        float N31 = sqrtf(7.f/fourpi / 12.f);
        float N32 = sqrtf(7.f/fourpi / 120.f);
        float N33 = sqrtf(7.f/fourpi / 720.f);
        float b;
        // n=0
        shr[p][0] = N00;               shi[p][0] = 0.f;
        // n=1
        shr[p][2] = N10*P10;           shi[p][2] = 0.f;
        b = N11*P11;
        shr[p][3] =  b*c1;             shi[p][3] =  b*s1;
        shr[p][1] = -b*c1;             shi[p][1] =  b*s1;   // (-1)^1 conj
        // n=2
        shr[p][6] = N20*P20;           shi[p][6] = 0.f;
        b = N21*P21;
        shr[p][7] =  b*c1;             shi[p][7] =  b*s1;
        shr[p][5] = -b*c1;             shi[p][5] =  b*s1;
        b = N22*P22;
        shr[p][8] =  b*c2;             shi[p][8] =  b*s2;
        shr[p][4] =  b*c2;             shi[p][4] = -b*s2;   // (+1) conj
        // n=3
        shr[p][12] = N30*P30;          shi[p][12] = 0.f;
        b = N31*P31;
        shr[p][13] =  b*c1;            shi[p][13] =  b*s1;
        shr[p][11] = -b*c1;            shi[p][11] =  b*s1;
        b = N32*P32;
        shr[p][14] =  b*c2;            shi[p][14] =  b*s2;
        shr[p][10] =  b*c2;            shi[p][10] = -b*s2;
        b = N33*P33;
        shr[p][15] =  b*c3;            shi[p][15] =  b*s3;
        shr[p][9]  = -b*c3;            shi[p][9]  =  b*s3;
        prof[p][0] = fmaxf(0.f, 1.f - fabsf(r - 1.f));
        prof[p][1] = fmaxf(0.f, 1.f - fabsf(r - 2.f));
    }
    __syncthreads();

    if (tid < 32) {
        int j = tid >> 4, h = tid & 15;
        float acc = 0.f;
        for (int p = 0; p < 125; ++p) {
            float pr = prof[p][j];
            acc += pr*pr*(shr[p][h]*shr[p][h] + shi[p][h]*shi[p][h]);
        }
        float nn = sqrtf(acc);
        norms[j][h] = (nn > 0.f) ? nn : 1.f;
    }
    if (tid == 0) {
        int cnt = 0;
        for (int pass = 0; pass < 3; ++pass)
            for (int p = 0; p < 125; ++p) {
                int d2 = p % 5, d1 = (p / 5) % 5, d0 = p / 25;
                int ix = d1 - 2, iy = d0 - 2, iz = d2 - 2;
                int r2 = ix*ix + iy*iy + iz*iz;
                int cls = (r2 == 1) ? 0
                        : (r2 == 2 || r2 == 3) ? 1
                        : (r2 == 4 || r2 == 5 || r2 == 6 || r2 == 8) ? 2 : -1;
                if (cls == pass) {
                    epos[cnt] = p;
                    edelta[cnt] = d0*(LY*LX) + d1*LX + d2;
                    ++cnt;
                }
            }
    }
    __syncthreads();

    for (int t = tid; t < 92*16; t += 256) {
        int e = t >> 4, h = t & 15;
        int p = epos[e];
        float c0 = prof[p][0] / norms[0][h];
        float c1v = prof[p][1] / norms[1][h];
        float4 v = make_float4(c0*shr[p][h], c0*shi[p][h], c1v*shr[p][h], c1v*shi[p][h]);
        ((float4*)(wsf + ATAB_F))[h*92 + e] = v;
    }
    // wT[n][f][c*2+j] <- w[c][f][j][n]  (w: [16][32][2][4])
    for (int t = tid; t < 4096; t += 256) {
        int n = t >> 10, f = (t >> 5) & 31, cj = t & 31, c = cj >> 1, j = cj & 1;
        wsf[WT_F + t] = w[((c*32 + f)*2 + j)*4 + n];
    }
    // pwT[i][fo] <- proj_w[fo][i]  (proj_w: [32][128])
    for (int t = tid; t < 4096; t += 256) {
        int i = t >> 5, fo = t & 31;
        wsf[PWT_F + t] = proj_w[fo*128 + i];
    }
    if (tid < 32) {
        float acc = proj_b[tid];
        for (int i = 0; i < 128; ++i) acc += proj_w[tid*128 + i] * spec_bias[i];
        wsf[OB_F + tid] = acc;
    }
}

__global__ __launch_bounds__(128) void ssh_main(
    const float* __restrict__ x, const float* __restrict__ cw,
    const float* __restrict__ cb, const float* __restrict__ ws,
    const int* __restrict__ edelta, float* __restrict__ out)
{
    const int tid = threadIdx.x;
    const int tx = tid & 7, ty = (tid >> 3) & 3, tz = tid >> 5;
    const int x0 = blockIdx.x * TX, y0 = blockIdx.y * TY, z0 = blockIdx.z * TZ;

    __shared__ float ldsx[16 * CSTRIDE];   // 48 KB

    for (int i = tid; i < 16 * CSTRIDE; i += 128) {
        int lx = i % LX; int t1 = i / LX;
        int ly = t1 % LY; int t2 = t1 / LY;
        int lz = t2 % LZ; int c  = t2 / LZ;
        int gx = x0 + lx - 2, gy = y0 + ly - 2, gz = z0 + lz - 2;
        float v = 0.f;
        if ((unsigned)gx < 48u && (unsigned)gy < 48u && (unsigned)gz < 48u)
            v = x[((c*48 + gz)*48 + gy)*48 + gx];
        ldsx[i] = v;
    }
    __syncthreads();

    const int base = tz*(LY*LX) + ty*LX + tx;
    const float4* __restrict__ atab = (const float4*)(ws + ATAB_F);
    const float*  __restrict__ wT   = ws + WT_F;
    const float*  __restrict__ pwT  = ws + PWT_F;
    const float*  __restrict__ obase= ws + OB_F;

    float outa[32];
#pragma unroll
    for (int i = 0; i < 32; ++i) outa[i] = 0.f;

#pragma unroll 1
    for (int h = 0; h < 16; ++h) {
        float zr0[16], zi0[16], zr1[16], zi1[16];
#pragma unroll
        for (int c = 0; c < 16; ++c) { zr0[c]=0.f; zi0[c]=0.f; zr1[c]=0.f; zi1[c]=0.f; }

        const float4* __restrict__ ae = atab + h*92;
        // segment 1: j0 only  [0,6)
#pragma unroll 1
        for (int e = 0; e < 6; ++e) {
            float4 cf = ae[e];
            int a = base + edelta[e];
#pragma unroll
            for (int c = 0; c < 16; ++c) {
                float xv = ldsx[c*CSTRIDE + a];
                zr0[c] += cf.x*xv; zi0[c] += cf.y*xv;
            }
        }
        // segment 2: both j  [6,26)
#pragma unroll 2
        for (int e = 6; e < 26; ++e) {
            float4 cf = ae[e];
            int a = base + edelta[e];
#pragma unroll
            for (int c = 0; c < 16; ++c) {
                float xv = ldsx[c*CSTRIDE + a];
                zr0[c] += cf.x*xv; zi0[c] += cf.y*xv;
                zr1[c] += cf.z*xv; zi1[c] += cf.w*xv;
            }
        }
        // segment 3: j1 only  [26,92)
#pragma unroll 2
        for (int e = 26; e < 92; ++e) {
            float4 cf = ae[e];
            int a = base + edelta[e];
#pragma unroll
            for (int c = 0; c < 16; ++c) {
                float xv = ldsx[c*CSTRIDE + a];
                zr1[c] += cf.z*xv; zi1[c] += cf.w*xv;
            }
        }

        const int n   = (h < 1) ? 0 : (h < 4) ? 1 : (h < 9) ? 2 : 3;
        const float invd = (n == 0) ? 1.f : (n == 1) ? (1.f/3.f) : (n == 2) ? (1.f/5.f) : (1.f/7.f);
        const float* __restrict__ wn = wT + n*1024;

#pragma unroll 2
        for (int f = 0; f < 32; ++f) {
            const float* __restrict__ wf = wn + f*32;
            float yr = 0.f, yi = 0.f;
#pragma unroll
            for (int c = 0; c < 16; ++c) {
                yr += wf[c*2]*zr0[c] + wf[c*2+1]*zr1[c];
                yi += wf[c*2]*zi0[c] + wf[c*2+1]*zi1[c];
            }
            if (h == 0) {
                float cpf = cb[f];
#pragma unroll
                for (int c = 0; c < 16; ++c)
                    cpf += cw[f*16 + c] * ldsx[c*CSTRIDE + base + (2*(LY*LX) + 2*LX + 2)];
                yr += cpf;
            }
            float s = (yr*yr + yi*yi) * invd;
            const float* __restrict__ pwf = pwT + (f*4 + n)*32;
#pragma unroll
            for (int fo = 0; fo < 32; ++fo) outa[fo] += pwf[fo]*s;
        }
    }

    const int gz = z0 + tz, gy = y0 + ty, gx = x0 + tx;
#pragma unroll 1
    for (int fo = 0; fo < 32; ++fo) {
        float v = obase[fo] + outa[fo];
        out[((fo*48 + gz)*48 + gy)*48 + gx] = fmaxf(v, 0.f);
    }
}

extern "C" void kernel_launch(void* const* d_in, const int* in_sizes, int n_in,
                              void* d_out, int out_size, void* d_ws, size_t ws_size,
                              hipStream_t stream) {
    const float* x  = (const float*)d_in[0];
    const float* w  = (const float*)d_in[1];
    const float* cw = (const float*)d_in[2];
    const float* cb = (const float*)d_in[3];
    const float* sb = (const float*)d_in[4];
    const float* pw = (const float*)d_in[5];
    const float* pb = (const float*)d_in[6];
    float* out = (float*)d_out;
    float* wsf = (float*)d_ws;
    int* edelta = (int*)((char*)d_ws + EDELTA_B);

    ssh_init<<<dim3(1), dim3(256), 0, stream>>>(w, pw, sb, pb, wsf, edelta);
    ssh_main<<<dim3(48/TX, 48/TY, 48/TZ), dim3(128), 0, stream>>>(x, cw, cb, wsf, edelta, out);
}

// Round 2
// 553.751 us; speedup vs baseline: 2.1250x; 2.1250x over previous
//
#include <hip/hip_runtime.h>
#include <math.h>

// ---------------------------------------------------------------------------
// SSHConv3D fused, round 2: bf16 LDS (channel-fastest), h-pair register
// blocking, ds_read_b128 channel loads.
// Constants: K=5, MD=3, HH=16, CIN=16, F=32, D=48, NJ=2.
//
//   z[c,j,h] = sum_e atom[e,j,h] * x[c, p+e]      (92 active offsets)
//   y[f,h]   = sum_{c,j} w[c,f,j,deg(h)] * z[c,j,h]  (+ central conv at h=0)
//   spec[f,n]= 1/(2n+1) sum_{h in deg n} |y[f,h]|^2  (+ spec_bias folded)
//   out[fo]  = relu( sum proj_w*spec + proj_b )
//
// ws layout (floats):
//   [0,     5888)  atab  : float4[16 h][92 e] = {ar_j0, ai_j0, ar_j1, ai_j1}
//   [5888,  9984)  wT    : [n][f][c*2+j]
//   [9984, 14080)  pwT   : [f*4+n][fo]
//   [14080,14112)  out_base[fo] = proj_b + proj_w . spec_bias
//   bytes [56448,56816) edelta : int[92]
// Entry segments: [0,6)=j0-only (r2=1), [6,26)=both (r2=2,3), [26,92)=j1-only.
// ---------------------------------------------------------------------------

#define TZ 4
#define TY 4
#define TX 8
#define LZ 8
#define LY 8
#define LX 12
#define NPOS (LZ*LY*LX)   // 768
#define CPAD 24           // ushorts per pos: 16 channels + 8 pad = 48B (16B-aligned)
#define CDEL (2*(LY*LX) + 2*LX + 2)

#define ATAB_F   0
#define WT_F     5888
#define PWT_F    9984
#define OB_F     14080
#define EDELTA_B 56448

__global__ __launch_bounds__(256) void ssh_init(
    const float* __restrict__ w, const float* __restrict__ proj_w,
    const float* __restrict__ spec_bias, const float* __restrict__ proj_b,
    float* __restrict__ wsf, int* __restrict__ edelta)
{
    __shared__ float shr[125][16];
    __shared__ float shi[125][16];
    __shared__ float prof[125][2];
    __shared__ float norms[2][16];
    __shared__ int epos[92];
    const int tid = threadIdx.x;
    const float fourpi = 4.0f * 3.14159265358979323846f;

    for (int p = tid; p < 125; p += 256) {
        int d2 = p % 5, d1 = (p / 5) % 5, d0 = p / 25;
        float xc = (float)(d1 - 2), yc = (float)(d0 - 2), zc = (float)(d2 - 2);
        float r2 = xc*xc + yc*yc + zc*zc;
        float r  = sqrtf(r2);
        float phi = atan2f(yc, xc);
        float ct = (r > 0.f) ? (zc / r) : 0.f;
        float st = sqrtf(fmaxf(0.f, 1.f - ct*ct));
        float c1 = cosf(phi), s1 = sinf(phi);
        float c2 = c1*c1 - s1*s1, s2 = 2.f*s1*c1;
        float c3 = c2*c1 - s2*s1, s3 = s2*c1 + c2*s1;
        float P10 = ct,              P11 = -st;
        float P20 = 0.5f*(3.f*ct*ct - 1.f), P21 = -3.f*ct*st, P22 = 3.f*st*st;
        float P30 = 0.5f*(5.f*ct*ct*ct - 3.f*ct);
        float P31 = -1.5f*(5.f*ct*ct - 1.f)*st;
        float P32 = 15.f*ct*st*st;
        float P33 = -15.f*st*st*st;
        float N00 = sqrtf(1.f/fourpi);
        float N10 = sqrtf(3.f/fourpi);
        float N11 = sqrtf(3.f/fourpi * 0.5f);
        float N20 = sqrtf(5.f/fourpi);
        float N21 = sqrtf(5.f/fourpi / 6.f);
        float N22 = sqrtf(5.f/fourpi / 24.f);
        float N30 = sqrtf(7.f/fourpi);
        float N31 = sqrtf(7.f/fourpi / 12.f);
        float N32 = sqrtf(7.f/fourpi / 120.f);
        float N33 = sqrtf(7.f/fourpi / 720.f);
        float b;
        shr[p][0] = N00;               shi[p][0] = 0.f;
        shr[p][2] = N10*P10;           shi[p][2] = 0.f;
        b = N11*P11;
        shr[p][3] =  b*c1;             shi[p][3] =  b*s1;
        shr[p][1] = -b*c1;             shi[p][1] =  b*s1;
        shr[p][6] = N20*P20;           shi[p][6] = 0.f;
        b = N21*P21;
        shr[p][7] =  b*c1;             shi[p][7] =  b*s1;
        shr[p][5] = -b*c1;             shi[p][5] =  b*s1;
        b = N22*P22;
        shr[p][8] =  b*c2;             shi[p][8] =  b*s2;
        shr[p][4] =  b*c2;             shi[p][4] = -b*s2;
        shr[p][12] = N30*P30;          shi[p][12] = 0.f;
        b = N31*P31;
        shr[p][13] =  b*c1;            shi[p][13] =  b*s1;
        shr[p][11] = -b*c1;            shi[p][11] =  b*s1;
        b = N32*P32;
        shr[p][14] =  b*c2;            shi[p][14] =  b*s2;
        shr[p][10] =  b*c2;            shi[p][10] = -b*s2;
        b = N33*P33;
        shr[p][15] =  b*c3;            shi[p][15] =  b*s3;
        shr[p][9]  = -b*c3;            shi[p][9]  =  b*s3;
        prof[p][0] = fmaxf(0.f, 1.f - fabsf(r - 1.f));
        prof[p][1] = fmaxf(0.f, 1.f - fabsf(r - 2.f));
    }
    __syncthreads();

    if (tid < 32) {
        int j = tid >> 4, h = tid & 15;
        float acc = 0.f;
        for (int p = 0; p < 125; ++p) {
            float pr = prof[p][j];
            acc += pr*pr*(shr[p][h]*shr[p][h] + shi[p][h]*shi[p][h]);
        }
        float nn = sqrtf(acc);
        norms[j][h] = (nn > 0.f) ? nn : 1.f;
    }
    // parallel rank computation for entry ordering (cls0 base 0, cls1 base 6, cls2 base 26)
    if (tid < 125) {
        int p = tid;
        int d2 = p % 5, d1 = (p / 5) % 5, d0 = p / 25;
        int ix = d1 - 2, iy = d0 - 2, iz = d2 - 2;
        int r2i = ix*ix + iy*iy + iz*iz;
        int cls = (r2i == 1) ? 0 : (r2i == 2 || r2i == 3) ? 1
                : (r2i == 4 || r2i == 5 || r2i == 6 || r2i == 8) ? 2 : -1;
        if (cls >= 0) {
            int rank = (cls == 0) ? 0 : (cls == 1) ? 6 : 26;
            for (int q = 0; q < p; ++q) {
                int e2 = q % 5, e1 = (q / 5) % 5, e0 = q / 25;
                int jx = e1 - 2, jy = e0 - 2, jz = e2 - 2;
                int s2i = jx*jx + jy*jy + jz*jz;
                int c2i = (s2i == 1) ? 0 : (s2i == 2 || s2i == 3) ? 1
                       : (s2i == 4 || s2i == 5 || s2i == 6 || s2i == 8) ? 2 : -1;
                rank += (c2i == cls) ? 1 : 0;
            }
            epos[rank] = p;
            edelta[rank] = d0*(LY*LX) + d1*LX + d2;
        }
    }
    __syncthreads();

    for (int t = tid; t < 92*16; t += 256) {
        int e = t >> 4, h = t & 15;
        int p = epos[e];
        float c0 = prof[p][0] / norms[0][h];
        float c1v = prof[p][1] / norms[1][h];
        float4 v = make_float4(c0*shr[p][h], c0*shi[p][h], c1v*shr[p][h], c1v*shi[p][h]);
        ((float4*)(wsf + ATAB_F))[h*92 + e] = v;
    }
    for (int t = tid; t < 4096; t += 256) {
        int n = t >> 10, f = (t >> 5) & 31, cj = t & 31, c = cj >> 1, j = cj & 1;
        wsf[WT_F + t] = w[((c*32 + f)*2 + j)*4 + n];
    }
    for (int t = tid; t < 4096; t += 256) {
        int i = t >> 5, fo = t & 31;
        wsf[PWT_F + t] = proj_w[fo*128 + i];
    }
    if (tid < 32) {
        float acc = proj_b[tid];
        for (int i = 0; i < 128; ++i) acc += proj_w[tid*128 + i] * spec_bias[i];
        wsf[OB_F + tid] = acc;
    }
}

// extract 2 bf16 (packed in one u32) to f32
#define EX2(arr, k, wrd) \
    arr[2*(k)]   = __int_as_float((int)((unsigned)(wrd) << 16)); \
    arr[2*(k)+1] = __int_as_float((int)((unsigned)(wrd) & 0xffff0000u));
#define EX16(arr, v0, v1) \
    EX2(arr,0,(v0).x); EX2(arr,1,(v0).y); EX2(arr,2,(v0).z); EX2(arr,3,(v0).w); \
    EX2(arr,4,(v1).x); EX2(arr,5,(v1).y); EX2(arr,6,(v1).z); EX2(arr,7,(v1).w);

// mixing + power spectrum + fused projection for one harmonic
#define MIX(hh, zr0, zi0, zr1, zi1) do { \
    const int n_ = ((hh) < 1) ? 0 : ((hh) < 4) ? 1 : ((hh) < 9) ? 2 : 3; \
    const float invd_ = ((hh) < 1) ? 1.f : ((hh) < 4) ? (1.f/3.f) : ((hh) < 9) ? 0.2f : (1.f/7.f); \
    const float* __restrict__ wn_ = wT + n_*1024; \
    float xc_[16]; \
    if ((hh) == 0) { \
        const int4* pc_ = (const int4*)(ldsb + (base + CDEL)*CPAD); \
        int4 u0_ = pc_[0], u1_ = pc_[1]; \
        EX16(xc_, u0_, u1_); \
    } \
    _Pragma("unroll 2") \
    for (int f = 0; f < 32; ++f) { \
        const float* __restrict__ wf_ = wn_ + f*32; \
        float yr_ = 0.f, yi_ = 0.f; \
        _Pragma("unroll") \
        for (int c = 0; c < 16; ++c) { \
            yr_ += wf_[2*c]*zr0[c] + wf_[2*c+1]*zr1[c]; \
            yi_ += wf_[2*c]*zi0[c] + wf_[2*c+1]*zi1[c]; \
        } \
        if ((hh) == 0) { \
            yr_ += cb[f]; \
            _Pragma("unroll") \
            for (int c = 0; c < 16; ++c) yr_ += cw[f*16 + c]*xc_[c]; \
        } \
        float s_ = (yr_*yr_ + yi_*yi_) * invd_; \
        const float* __restrict__ pwf_ = pwT + (f*4 + n_)*32; \
        _Pragma("unroll") \
        for (int fo = 0; fo < 32; ++fo) outa[fo] += pwf_[fo]*s_; \
    } \
} while (0)

__global__ __launch_bounds__(128, 2) void ssh_main(
    const float* __restrict__ x, const float* __restrict__ cw,
    const float* __restrict__ cb, const float* __restrict__ ws,
    const int* __restrict__ edelta, float* __restrict__ out)
{
    const int tid = threadIdx.x;
    const int tx = tid & 7, ty = (tid >> 3) & 3, tz = tid >> 5;
    const int x0 = blockIdx.x * TX, y0 = blockIdx.y * TY, z0 = blockIdx.z * TZ;

    __shared__ __align__(16) unsigned short ldsb[NPOS * CPAD];   // 36.9 KB

    // stage x -> bf16 LDS, channel-fastest [pos][CPAD]
    for (int i = tid; i < NPOS * 16; i += 128) {
        int c = i / NPOS;
        int pos = i - c * NPOS;
        int lx = pos % LX; int t1 = pos / LX;
        int ly = t1 % LY;  int lz = t1 / LY;
        int gx = x0 + lx - 2, gy = y0 + ly - 2, gz = z0 + lz - 2;
        unsigned short hv = 0;
        if ((unsigned)gx < 48u && (unsigned)gy < 48u && (unsigned)gz < 48u) {
            unsigned int u = __float_as_uint(x[((c*48 + gz)*48 + gy)*48 + gx]);
            u = (u + 0x7fffu + ((u >> 16) & 1u)) >> 16;   // RNE to bf16
            hv = (unsigned short)u;
        }
        ldsb[pos * CPAD + c] = hv;
    }
    __syncthreads();

    const int base = tz*(LY*LX) + ty*LX + tx;
    const float4* __restrict__ atab = (const float4*)(ws + ATAB_F);
    const float*  __restrict__ wT   = ws + WT_F;
    const float*  __restrict__ pwT  = ws + PWT_F;
    const float*  __restrict__ obase= ws + OB_F;

    float outa[32];
#pragma unroll
    for (int i = 0; i < 32; ++i) outa[i] = 0.f;

#pragma unroll 1
    for (int hp = 0; hp < 8; ++hp) {
        const int h0 = hp * 2, h1 = h0 + 1;
        float ar0[16], ai0[16], ar1[16], ai1[16];
        float br0[16], bi0[16], br1[16], bi1[16];
#pragma unroll
        for (int c = 0; c < 16; ++c) {
            ar0[c]=0.f; ai0[c]=0.f; ar1[c]=0.f; ai1[c]=0.f;
            br0[c]=0.f; bi0[c]=0.f; br1[c]=0.f; bi1[c]=0.f;
        }
        const float4* __restrict__ ae0 = atab + h0*92;
        const float4* __restrict__ ae1 = atab + h1*92;

        // segment 1: j0 only [0,6)
#pragma unroll 2
        for (int e = 0; e < 6; ++e) {
            float4 c0 = ae0[e], c1 = ae1[e];
            int a = base + edelta[e];
            const int4* p = (const int4*)(ldsb + a*CPAD);
            int4 v0 = p[0], v1 = p[1];
            float xv[16];
            EX16(xv, v0, v1);
#pragma unroll
            for (int c = 0; c < 16; ++c) {
                ar0[c] += c0.x*xv[c]; ai0[c] += c0.y*xv[c];
                br0[c] += c1.x*xv[c]; bi0[c] += c1.y*xv[c];
            }
        }
        // segment 2: both j [6,26)
#pragma unroll 2
        for (int e = 6; e < 26; ++e) {
            float4 c0 = ae0[e], c1 = ae1[e];
            int a = base + edelta[e];
            const int4* p = (const int4*)(ldsb + a*CPAD);
            int4 v0 = p[0], v1 = p[1];
            float xv[16];
            EX16(xv, v0, v1);
#pragma unroll
            for (int c = 0; c < 16; ++c) {
                ar0[c] += c0.x*xv[c]; ai0[c] += c0.y*xv[c];
                ar1[c] += c0.z*xv[c]; ai1[c] += c0.w*xv[c];
                br0[c] += c1.x*xv[c]; bi0[c] += c1.y*xv[c];
                br1[c] += c1.z*xv[c]; bi1[c] += c1.w*xv[c];
            }
        }
        // segment 3: j1 only [26,92)
#pragma unroll 2
        for (int e = 26; e < 92; ++e) {
            float4 c0 = ae0[e], c1 = ae1[e];
            int a = base + edelta[e];
            const int4* p = (const int4*)(ldsb + a*CPAD);
            int4 v0 = p[0], v1 = p[1];
            float xv[16];
            EX16(xv, v0, v1);
#pragma unroll
            for (int c = 0; c < 16; ++c) {
                ar1[c] += c0.z*xv[c]; ai1[c] += c0.w*xv[c];
                br1[c] += c1.z*xv[c]; bi1[c] += c1.w*xv[c];
            }
        }

        MIX(h0, ar0, ai0, ar1, ai1);
        MIX(h1, br0, bi0, br1, bi1);
    }

    const int gz = z0 + tz, gy = y0 + ty, gx = x0 + tx;
#pragma unroll 1
    for (int fo = 0; fo < 32; ++fo) {
        float v = obase[fo] + outa[fo];
        out[((fo*48 + gz)*48 + gy)*48 + gx] = fmaxf(v, 0.f);
    }
}

extern "C" void kernel_launch(void* const* d_in, const int* in_sizes, int n_in,
                              void* d_out, int out_size, void* d_ws, size_t ws_size,
                              hipStream_t stream) {
    const float* x  = (const float*)d_in[0];
    const float* w  = (const float*)d_in[1];
    const float* cw = (const float*)d_in[2];
    const float* cb = (const float*)d_in[3];
    const float* sb = (const float*)d_in[4];
    const float* pw = (const float*)d_in[5];
    const float* pb = (const float*)d_in[6];
    float* out = (float*)d_out;
    float* wsf = (float*)d_ws;
    int* edelta = (int*)((char*)d_ws + EDELTA_B);

    ssh_init<<<dim3(1), dim3(256), 0, stream>>>(w, pw, sb, pb, wsf, edelta);
    ssh_main<<<dim3(48/TX, 48/TY, 48/TZ), dim3(128), 0, stream>>>(x, cw, cb, wsf, edelta, out);
}

// Round 3
// 279.784 us; speedup vs baseline: 4.2059x; 1.9792x over previous
//
#include <hip/hip_runtime.h>
#include <hip/hip_fp16.h>
#include <math.h>

// ---------------------------------------------------------------------------
// SSHConv3D fused, round 3: full __half2 packed-f16 datapath (v_pk_fma_f16 at
// 2x f32 rate), zero-extraction LDS reads, 2-way h-split for occupancy.
// Constants: K=5, MD=3, HH=16, CIN=16, F=32, D=48, NJ=2.
//
//   z[c,j,h] = sum_e atom[e,j,h] * x[c, p+e]      (92 active offsets)
//   y[f,h]   = sum_{c,j} w[c,f,j,deg(h)] * z[c,j,h]  (+ central conv at h=0)
//   spec     = per-degree power spectrum; proj 1x1x1 + ReLU fused.
//
// ws layout (bytes):
//   [0,     23552) atab2 : h2[16 h][92 e][4] = {(ar0,ar0),(ai0,ai0),(ar1,ar1),(ai1,ai1)}
//   [23552, 31744) wT2   : h2[n][f][j][8 cp] = (w[c0],w[c1]) pairs
//   [31744, 32768) cw2   : h2[f][8 cp]
//   [32768, 49152) pwT   : f32[(f*4+n)][fo]
//   [49152, 49280) obase : f32[32] = proj_b + proj_w . spec_bias
//   [49280, 49648) edelta: int[92]  (byte offsets, pre-scaled by 48)
// Entry segments: [0,6)=j0-only, [6,26)=both j, [26,92)=j1-only.
// ---------------------------------------------------------------------------

#define TX 8
#define TY 4
#define TZ 4
#define LXX 12
#define LYY 8
#define LZZ 8
#define NPOS 768
#define CPAD 24           // halves per pos = 48B (16B-aligned, conflict-free stride)
#define POSB 48

#define ATAB2_B 0
#define WT2_B   23552
#define CW2_B   31744
#define PWT_B   32768
#define OB_B    49152
#define ED_B    49280

typedef __half2 h2;
union I4H { int4 v; h2 h[4]; };

__global__ __launch_bounds__(256) void ssh_init(
    const float* __restrict__ w, const float* __restrict__ cw,
    const float* __restrict__ proj_w, const float* __restrict__ spec_bias,
    const float* __restrict__ proj_b, char* __restrict__ wsb)
{
    __shared__ float shr[125][16];
    __shared__ float shi[125][16];
    __shared__ float prof[125][2];
    __shared__ float norms[2][16];
    __shared__ int epos[92];
    const int tid = threadIdx.x;
    const float fourpi = 4.0f * 3.14159265358979323846f;

    for (int p = tid; p < 125; p += 256) {
        int d2 = p % 5, d1 = (p / 5) % 5, d0 = p / 25;
        float xc = (float)(d1 - 2), yc = (float)(d0 - 2), zc = (float)(d2 - 2);
        float r2 = xc*xc + yc*yc + zc*zc;
        float r  = sqrtf(r2);
        float phi = atan2f(yc, xc);
        float ct = (r > 0.f) ? (zc / r) : 0.f;
        float st = sqrtf(fmaxf(0.f, 1.f - ct*ct));
        float c1 = cosf(phi), s1 = sinf(phi);
        float c2 = c1*c1 - s1*s1, s2 = 2.f*s1*c1;
        float c3 = c2*c1 - s2*s1, s3 = s2*c1 + c2*s1;
        float P10 = ct,              P11 = -st;
        float P20 = 0.5f*(3.f*ct*ct - 1.f), P21 = -3.f*ct*st, P22 = 3.f*st*st;
        float P30 = 0.5f*(5.f*ct*ct*ct - 3.f*ct);
        float P31 = -1.5f*(5.f*ct*ct - 1.f)*st;
        float P32 = 15.f*ct*st*st;
        float P33 = -15.f*st*st*st;
        float N00 = sqrtf(1.f/fourpi);
        float N10 = sqrtf(3.f/fourpi);
        float N11 = sqrtf(3.f/fourpi * 0.5f);
        float N20 = sqrtf(5.f/fourpi);
        float N21 = sqrtf(5.f/fourpi / 6.f);
        float N22 = sqrtf(5.f/fourpi / 24.f);
        float N30 = sqrtf(7.f/fourpi);
        float N31 = sqrtf(7.f/fourpi / 12.f);
        float N32 = sqrtf(7.f/fourpi / 120.f);
        float N33 = sqrtf(7.f/fourpi / 720.f);
        float b;
        shr[p][0] = N00;               shi[p][0] = 0.f;
        shr[p][2] = N10*P10;           shi[p][2] = 0.f;
        b = N11*P11;
        shr[p][3] =  b*c1;             shi[p][3] =  b*s1;
        shr[p][1] = -b*c1;             shi[p][1] =  b*s1;
        shr[p][6] = N20*P20;           shi[p][6] = 0.f;
        b = N21*P21;
        shr[p][7] =  b*c1;             shi[p][7] =  b*s1;
        shr[p][5] = -b*c1;             shi[p][5] =  b*s1;
        b = N22*P22;
        shr[p][8] =  b*c2;             shi[p][8] =  b*s2;
        shr[p][4] =  b*c2;             shi[p][4] = -b*s2;
        shr[p][12] = N30*P30;          shi[p][12] = 0.f;
        b = N31*P31;
        shr[p][13] =  b*c1;            shi[p][13] =  b*s1;
        shr[p][11] = -b*c1;            shi[p][11] =  b*s1;
        b = N32*P32;
        shr[p][14] =  b*c2;            shi[p][14] =  b*s2;
        shr[p][10] =  b*c2;            shi[p][10] = -b*s2;
        b = N33*P33;
        shr[p][15] =  b*c3;            shi[p][15] =  b*s3;
        shr[p][9]  = -b*c3;            shi[p][9]  =  b*s3;
        prof[p][0] = fmaxf(0.f, 1.f - fabsf(r - 1.f));
        prof[p][1] = fmaxf(0.f, 1.f - fabsf(r - 2.f));
    }
    __syncthreads();

    if (tid < 32) {
        int j = tid >> 4, h = tid & 15;
        float acc = 0.f;
        for (int p = 0; p < 125; ++p) {
            float pr = prof[p][j];
            acc += pr*pr*(shr[p][h]*shr[p][h] + shi[p][h]*shi[p][h]);
        }
        float nn = sqrtf(acc);
        norms[j][h] = (nn > 0.f) ? nn : 1.f;
    }
    // entry ordering via rank (cls0 base 0, cls1 base 6, cls2 base 26)
    if (tid < 125) {
        int p = tid;
        int d2 = p % 5, d1 = (p / 5) % 5, d0 = p / 25;
        int ix = d1 - 2, iy = d0 - 2, iz = d2 - 2;
        int r2i = ix*ix + iy*iy + iz*iz;
        int cls = (r2i == 1) ? 0 : (r2i == 2 || r2i == 3) ? 1
                : (r2i == 4 || r2i == 5 || r2i == 6 || r2i == 8) ? 2 : -1;
        if (cls >= 0) {
            int rank = (cls == 0) ? 0 : (cls == 1) ? 6 : 26;
            for (int q = 0; q < p; ++q) {
                int e2 = q % 5, e1 = (q / 5) % 5, e0 = q / 25;
                int jx = e1 - 2, jy = e0 - 2, jz = e2 - 2;
                int s2i = jx*jx + jy*jy + jz*jz;
                int c2i = (s2i == 1) ? 0 : (s2i == 2 || s2i == 3) ? 1
                       : (s2i == 4 || s2i == 5 || s2i == 6 || s2i == 8) ? 2 : -1;
                rank += (c2i == cls) ? 1 : 0;
            }
            epos[rank] = p;
            ((int*)(wsb + ED_B))[rank] = (d0*(LYY*LXX) + d1*LXX + d2) * POSB;
        }
    }
    __syncthreads();

    h2* at2 = (h2*)(wsb + ATAB2_B);
    for (int t = tid; t < 92*16; t += 256) {
        int e = t >> 4, h = t & 15;
        int p = epos[e];
        float c0 = prof[p][0] / norms[0][h];
        float c1v = prof[p][1] / norms[1][h];
        at2[(h*92+e)*4 + 0] = __float2half2_rn(c0*shr[p][h]);
        at2[(h*92+e)*4 + 1] = __float2half2_rn(c0*shi[p][h]);
        at2[(h*92+e)*4 + 2] = __float2half2_rn(c1v*shr[p][h]);
        at2[(h*92+e)*4 + 3] = __float2half2_rn(c1v*shi[p][h]);
    }
    // wT2: h2 index = n*512 + f*16 + j*8 + cp
    h2* wt2h = (h2*)(wsb + WT2_B);
    for (int t = tid; t < 2048; t += 256) {
        int n = t >> 9, f = (t >> 4) & 31, j = (t >> 3) & 1, cp = t & 7;
        float a = w[((2*cp*32 + f)*2 + j)*4 + n];
        float b = w[(((2*cp+1)*32 + f)*2 + j)*4 + n];
        wt2h[t] = __halves2half2(__float2half(a), __float2half(b));
    }
    // cw2: h2 index = f*8 + cp
    h2* cw2h = (h2*)(wsb + CW2_B);
    for (int t = tid; t < 256; t += 256) {
        int f = t >> 3, cp = t & 7;
        cw2h[t] = __halves2half2(__float2half(cw[f*16 + 2*cp]),
                                 __float2half(cw[f*16 + 2*cp + 1]));
    }
    // pwT f32 [(f*4+n)][fo]
    float* pwT = (float*)(wsb + PWT_B);
    for (int t = tid; t < 4096; t += 256) {
        int i = t >> 5, fo = t & 31;
        pwT[t] = proj_w[fo*128 + i];
    }
    if (tid < 32) {
        float acc = proj_b[tid];
        for (int i = 0; i < 128; ++i) acc += proj_w[tid*128 + i] * spec_bias[i];
        ((float*)(wsb + OB_B))[tid] = acc;
    }
}

// ---------------- conv passes --------------------------------------------

__device__ __forceinline__ void conv2(const __half* __restrict__ ldsh, int baseb,
    const int4* __restrict__ aA, const int4* __restrict__ aB,
    const int* __restrict__ ed, h2 (&zA)[4][8], h2 (&zB)[4][8])
{
#pragma unroll
    for (int r = 0; r < 4; ++r)
#pragma unroll
        for (int q = 0; q < 8; ++q) { zA[r][q] = __float2half2_rn(0.f); zB[r][q] = __float2half2_rn(0.f); }

#pragma unroll 2
    for (int e = 0; e < 6; ++e) {           // j0 only
        I4H ca, cb_, x0, x1;
        ca.v = aA[e]; cb_.v = aB[e];
        const int4* p = (const int4*)((const char*)ldsh + baseb + ed[e]);
        x0.v = p[0]; x1.v = p[1];
#pragma unroll
        for (int q = 0; q < 4; ++q) {
            zA[0][q]   = __hfma2(ca.h[0],  x0.h[q], zA[0][q]);
            zA[1][q]   = __hfma2(ca.h[1],  x0.h[q], zA[1][q]);
            zB[0][q]   = __hfma2(cb_.h[0], x0.h[q], zB[0][q]);
            zB[1][q]   = __hfma2(cb_.h[1], x0.h[q], zB[1][q]);
            zA[0][q+4] = __hfma2(ca.h[0],  x1.h[q], zA[0][q+4]);
            zA[1][q+4] = __hfma2(ca.h[1],  x1.h[q], zA[1][q+4]);
            zB[0][q+4] = __hfma2(cb_.h[0], x1.h[q], zB[0][q+4]);
            zB[1][q+4] = __hfma2(cb_.h[1], x1.h[q], zB[1][q+4]);
        }
    }
#pragma unroll 2
    for (int e = 6; e < 26; ++e) {          // both j
        I4H ca, cb_, x0, x1;
        ca.v = aA[e]; cb_.v = aB[e];
        const int4* p = (const int4*)((const char*)ldsh + baseb + ed[e]);
        x0.v = p[0]; x1.v = p[1];
#pragma unroll
        for (int q = 0; q < 4; ++q) {
            zA[0][q]   = __hfma2(ca.h[0],  x0.h[q], zA[0][q]);
            zA[1][q]   = __hfma2(ca.h[1],  x0.h[q], zA[1][q]);
            zA[2][q]   = __hfma2(ca.h[2],  x0.h[q], zA[2][q]);
            zA[3][q]   = __hfma2(ca.h[3],  x0.h[q], zA[3][q]);
            zB[0][q]   = __hfma2(cb_.h[0], x0.h[q], zB[0][q]);
            zB[1][q]   = __hfma2(cb_.h[1], x0.h[q], zB[1][q]);
            zB[2][q]   = __hfma2(cb_.h[2], x0.h[q], zB[2][q]);
            zB[3][q]   = __hfma2(cb_.h[3], x0.h[q], zB[3][q]);
            zA[0][q+4] = __hfma2(ca.h[0],  x1.h[q], zA[0][q+4]);
            zA[1][q+4] = __hfma2(ca.h[1],  x1.h[q], zA[1][q+4]);
            zA[2][q+4] = __hfma2(ca.h[2],  x1.h[q], zA[2][q+4]);
            zA[3][q+4] = __hfma2(ca.h[3],  x1.h[q], zA[3][q+4]);
            zB[0][q+4] = __hfma2(cb_.h[0], x1.h[q], zB[0][q+4]);
            zB[1][q+4] = __hfma2(cb_.h[1], x1.h[q], zB[1][q+4]);
            zB[2][q+4] = __hfma2(cb_.h[2], x1.h[q], zB[2][q+4]);
            zB[3][q+4] = __hfma2(cb_.h[3], x1.h[q], zB[3][q+4]);
        }
    }
#pragma unroll 2
    for (int e = 26; e < 92; ++e) {         // j1 only
        I4H ca, cb_, x0, x1;
        ca.v = aA[e]; cb_.v = aB[e];
        const int4* p = (const int4*)((const char*)ldsh + baseb + ed[e]);
        x0.v = p[0]; x1.v = p[1];
#pragma unroll
        for (int q = 0; q < 4; ++q) {
            zA[2][q]   = __hfma2(ca.h[2],  x0.h[q], zA[2][q]);
            zA[3][q]   = __hfma2(ca.h[3],  x0.h[q], zA[3][q]);
            zB[2][q]   = __hfma2(cb_.h[2], x0.h[q], zB[2][q]);
            zB[3][q]   = __hfma2(cb_.h[3], x0.h[q], zB[3][q]);
            zA[2][q+4] = __hfma2(ca.h[2],  x1.h[q], zA[2][q+4]);
            zA[3][q+4] = __hfma2(ca.h[3],  x1.h[q], zA[3][q+4]);
            zB[2][q+4] = __hfma2(cb_.h[2], x1.h[q], zB[2][q+4]);
            zB[3][q+4] = __hfma2(cb_.h[3], x1.h[q], zB[3][q+4]);
        }
    }
}

__device__ __forceinline__ void conv1(const __half* __restrict__ ldsh, int baseb,
    const int4* __restrict__ aA, const int* __restrict__ ed, h2 (&zA)[4][8])
{
#pragma unroll
    for (int r = 0; r < 4; ++r)
#pragma unroll
        for (int q = 0; q < 8; ++q) zA[r][q] = __float2half2_rn(0.f);

#pragma unroll 2
    for (int e = 0; e < 6; ++e) {
        I4H ca, x0, x1;
        ca.v = aA[e];
        const int4* p = (const int4*)((const char*)ldsh + baseb + ed[e]);
        x0.v = p[0]; x1.v = p[1];
#pragma unroll
        for (int q = 0; q < 4; ++q) {
            zA[0][q]   = __hfma2(ca.h[0], x0.h[q], zA[0][q]);
            zA[1][q]   = __hfma2(ca.h[1], x0.h[q], zA[1][q]);
            zA[0][q+4] = __hfma2(ca.h[0], x1.h[q], zA[0][q+4]);
            zA[1][q+4] = __hfma2(ca.h[1], x1.h[q], zA[1][q+4]);
        }
    }
#pragma unroll 2
    for (int e = 6; e < 26; ++e) {
        I4H ca, x0, x1;
        ca.v = aA[e];
        const int4* p = (const int4*)((const char*)ldsh + baseb + ed[e]);
        x0.v = p[0]; x1.v = p[1];
#pragma unroll
        for (int q = 0; q < 4; ++q) {
            zA[0][q]   = __hfma2(ca.h[0], x0.h[q], zA[0][q]);
            zA[1][q]   = __hfma2(ca.h[1], x0.h[q], zA[1][q]);
            zA[2][q]   = __hfma2(ca.h[2], x0.h[q], zA[2][q]);
            zA[3][q]   = __hfma2(ca.h[3], x0.h[q], zA[3][q]);
            zA[0][q+4] = __hfma2(ca.h[0], x1.h[q], zA[0][q+4]);
            zA[1][q+4] = __hfma2(ca.h[1], x1.h[q], zA[1][q+4]);
            zA[2][q+4] = __hfma2(ca.h[2], x1.h[q], zA[2][q+4]);
            zA[3][q+4] = __hfma2(ca.h[3], x1.h[q], zA[3][q+4]);
        }
    }
#pragma unroll 2
    for (int e = 26; e < 92; ++e) {
        I4H ca, x0, x1;
        ca.v = aA[e];
        const int4* p = (const int4*)((const char*)ldsh + baseb + ed[e]);
        x0.v = p[0]; x1.v = p[1];
#pragma unroll
        for (int q = 0; q < 4; ++q) {
            zA[2][q]   = __hfma2(ca.h[2], x0.h[q], zA[2][q]);
            zA[3][q]   = __hfma2(ca.h[3], x0.h[q], zA[3][q]);
            zA[2][q+4] = __hfma2(ca.h[2], x1.h[q], zA[2][q+4]);
            zA[3][q+4] = __hfma2(ca.h[3], x1.h[q], zA[3][q+4]);
        }
    }
}

// ---------------- mixing + spectrum + fused projection --------------------

template<int N, bool CENTRAL>
__device__ __forceinline__ void mix_h(const h2 (&z)[4][8],
    const int4* __restrict__ wt2n, const int4* __restrict__ cw2,
    const float* __restrict__ cbp, const __half* __restrict__ ldsh, int baseb,
    const float* __restrict__ pwT, float2 (&outa)[16])
{
    const float invd = (N==0) ? 1.f : (N==1) ? (1.f/3.f) : (N==2) ? 0.2f : (1.f/7.f);
    h2 xc[8];
    if (CENTRAL) {
        const int4* pc = (const int4*)((const char*)ldsh + baseb + 218*POSB);
        I4H xc0, xc1; xc0.v = pc[0]; xc1.v = pc[1];
#pragma unroll
        for (int q = 0; q < 4; ++q) { xc[q] = xc0.h[q]; xc[q+4] = xc1.h[q]; }
    }
#pragma unroll 2
    for (int f = 0; f < 32; ++f) {
        I4H w00, w01, w10, w11;
        w00.v = wt2n[f*4+0]; w01.v = wt2n[f*4+1];
        w10.v = wt2n[f*4+2]; w11.v = wt2n[f*4+3];
        h2 yr = __float2half2_rn(0.f), yi = __float2half2_rn(0.f);
#pragma unroll
        for (int q = 0; q < 4; ++q) {
            yr = __hfma2(w00.h[q], z[0][q],   yr);
            yr = __hfma2(w01.h[q], z[0][q+4], yr);
            yr = __hfma2(w10.h[q], z[2][q],   yr);
            yr = __hfma2(w11.h[q], z[2][q+4], yr);
            yi = __hfma2(w00.h[q], z[1][q],   yi);
            yi = __hfma2(w01.h[q], z[1][q+4], yi);
            yi = __hfma2(w10.h[q], z[3][q],   yi);
            yi = __hfma2(w11.h[q], z[3][q+4], yi);
        }
        float yrf = __low2float(yr) + __high2float(yr);
        float yif = __low2float(yi) + __high2float(yi);
        if (CENTRAL) {
            I4H c0, c1; c0.v = cw2[f*2]; c1.v = cw2[f*2+1];
            h2 acc = __float2half2_rn(0.f);
#pragma unroll
            for (int q = 0; q < 4; ++q) {
                acc = __hfma2(c0.h[q], xc[q],   acc);
                acc = __hfma2(c1.h[q], xc[q+4], acc);
            }
            yrf += cbp[f] + __low2float(acc) + __high2float(acc);
        }
        float s = (yrf*yrf + yif*yif) * invd;
        const float2* pw2 = (const float2*)(pwT + (f*4 + N)*32);
#pragma unroll
        for (int k = 0; k < 16; ++k) {
            float2 t = pw2[k];
            outa[k].x = fmaf(t.x, s, outa[k].x);
            outa[k].y = fmaf(t.y, s, outa[k].y);
        }
    }
}

__global__ __launch_bounds__(256, 3) void ssh_main(
    const float* __restrict__ x, const float* __restrict__ cb,
    const char* __restrict__ wsb, float* __restrict__ out)
{
    __shared__ __align__(16) __half ldsh[NPOS * CPAD];   // 36864 B
    const int tid = threadIdx.x;
    const int x0 = blockIdx.x * TX, y0 = blockIdx.y * TY, z0 = blockIdx.z * TZ;

    // stage x -> f16 LDS, channel-fastest, 2 channels per write (b32)
    for (int i = tid; i < NPOS * 8; i += 256) {
        int cp = i / NPOS;
        int pos = i - cp * NPOS;
        int lx = pos % LXX; int t1 = pos / LXX;
        int ly = t1 % LYY;  int lz = t1 / LYY;
        int gx = x0 + lx - 2, gy = y0 + ly - 2, gz = z0 + lz - 2;
        h2 hv = __float2half2_rn(0.f);
        if ((unsigned)gx < 48u && (unsigned)gy < 48u && (unsigned)gz < 48u) {
            int gi = ((2*cp*48 + gz)*48 + gy)*48 + gx;
            hv = __floats2half2_rn(x[gi], x[gi + 48*48*48]);
        }
        *(h2*)(ldsh + pos*CPAD + 2*cp) = hv;
    }
    __syncthreads();

    const int hf  = tid >> 7;
    const int vid = tid & 127;
    const int tx = vid & 7, ty = (vid >> 3) & 3, tz = vid >> 5;
    const int baseb = (tz*(LYY*LXX) + ty*LXX + tx) * POSB;

    const int4* __restrict__ atab = (const int4*)(wsb + ATAB2_B);
    const int4* __restrict__ wt2  = (const int4*)(wsb + WT2_B);
    const int4* __restrict__ cw2  = (const int4*)(wsb + CW2_B);
    const float* __restrict__ pwT = (const float*)(wsb + PWT_B);
    const float* __restrict__ obase = (const float*)(wsb + OB_B);
    const int* __restrict__ ed    = (const int*)(wsb + ED_B);

    float2 outa[16];
#pragma unroll
    for (int k = 0; k < 16; ++k) outa[k] = make_float2(0.f, 0.f);

    h2 zA[4][8], zB[4][8];
    if (hf == 0) {
        // n=3 (h 9..15), then n=0 (h 0, + central)
        conv2(ldsh, baseb, atab + 9*92,  atab + 10*92, ed, zA, zB);
        mix_h<3,false>(zA, wt2 + 3*128, cw2, cb, ldsh, baseb, pwT, outa);
        mix_h<3,false>(zB, wt2 + 3*128, cw2, cb, ldsh, baseb, pwT, outa);
        conv2(ldsh, baseb, atab + 11*92, atab + 12*92, ed, zA, zB);
        mix_h<3,false>(zA, wt2 + 3*128, cw2, cb, ldsh, baseb, pwT, outa);
        mix_h<3,false>(zB, wt2 + 3*128, cw2, cb, ldsh, baseb, pwT, outa);
        conv2(ldsh, baseb, atab + 13*92, atab + 14*92, ed, zA, zB);
        mix_h<3,false>(zA, wt2 + 3*128, cw2, cb, ldsh, baseb, pwT, outa);
        mix_h<3,false>(zB, wt2 + 3*128, cw2, cb, ldsh, baseb, pwT, outa);
        conv1(ldsh, baseb, atab + 15*92, ed, zA);
        mix_h<3,false>(zA, wt2 + 3*128, cw2, cb, ldsh, baseb, pwT, outa);
        conv1(ldsh, baseb, atab + 0*92, ed, zA);
        mix_h<0,true>(zA, wt2 + 0*128, cw2, cb, ldsh, baseb, pwT, outa);
    } else {
        // n=1 (h 1..3), n=2 (h 4..8)
        conv2(ldsh, baseb, atab + 1*92, atab + 2*92, ed, zA, zB);
        mix_h<1,false>(zA, wt2 + 1*128, cw2, cb, ldsh, baseb, pwT, outa);
        mix_h<1,false>(zB, wt2 + 1*128, cw2, cb, ldsh, baseb, pwT, outa);
        conv1(ldsh, baseb, atab + 3*92, ed, zA);
        mix_h<1,false>(zA, wt2 + 1*128, cw2, cb, ldsh, baseb, pwT, outa);
        conv2(ldsh, baseb, atab + 4*92, atab + 5*92, ed, zA, zB);
        mix_h<2,false>(zA, wt2 + 2*128, cw2, cb, ldsh, baseb, pwT, outa);
        mix_h<2,false>(zB, wt2 + 2*128, cw2, cb, ldsh, baseb, pwT, outa);
        conv2(ldsh, baseb, atab + 6*92, atab + 7*92, ed, zA, zB);
        mix_h<2,false>(zA, wt2 + 2*128, cw2, cb, ldsh, baseb, pwT, outa);
        mix_h<2,false>(zB, wt2 + 2*128, cw2, cb, ldsh, baseb, pwT, outa);
        conv1(ldsh, baseb, atab + 8*92, ed, zA);
        mix_h<2,false>(zA, wt2 + 2*128, cw2, cb, ldsh, baseb, pwT, outa);
    }

    // merge halves through LDS (x-tile is dead now); stride 33 avoids conflicts
    __syncthreads();
    float* lmerge = (float*)ldsh;
    if (hf == 1) {
#pragma unroll
        for (int k = 0; k < 16; ++k) {
            lmerge[vid*33 + 2*k]     = outa[k].x;
            lmerge[vid*33 + 2*k + 1] = outa[k].y;
        }
    }
    __syncthreads();
    if (hf == 0) {
        const int gz = z0 + tz, gy = y0 + ty, gx = x0 + tx;
#pragma unroll
        for (int k = 0; k < 16; ++k) {
            float v0 = obase[2*k]   + outa[k].x + lmerge[vid*33 + 2*k];
            float v1 = obase[2*k+1] + outa[k].y + lmerge[vid*33 + 2*k + 1];
            out[(((2*k)*48   + gz)*48 + gy)*48 + gx] = fmaxf(v0, 0.f);
            out[(((2*k+1)*48 + gz)*48 + gy)*48 + gx] = fmaxf(v1, 0.f);
        }
    }
}

extern "C" void kernel_launch(void* const* d_in, const int* in_sizes, int n_in,
                              void* d_out, int out_size, void* d_ws, size_t ws_size,
                              hipStream_t stream) {
    const float* x  = (const float*)d_in[0];
    const float* w  = (const float*)d_in[1];
    const float* cw = (const float*)d_in[2];
    const float* cb = (const float*)d_in[3];
    const float* sb = (const float*)d_in[4];
    const float* pw = (const float*)d_in[5];
    const float* pb = (const float*)d_in[6];
    float* out = (float*)d_out;
    char* wsb = (char*)d_ws;

    ssh_init<<<dim3(1), dim3(256), 0, stream>>>(w, cw, pw, sb, pb, wsb);
    ssh_main<<<dim3(48/TX, 48/TY, 48/TZ), dim3(256), 0, stream>>>(x, cb, wsb, out);
}

// Round 4
// 169.753 us; speedup vs baseline: 6.9320x; 1.6482x over previous
//
#include <hip/hip_runtime.h>
#include <hip/hip_fp16.h>
#include <math.h>

// ---------------------------------------------------------------------------
// SSHConv3D fused, round 4: m>=0 conjugate-symmetry halving of harmonic work.
// |y[f,-m]| == |y[f,m]| exactly (real input, real weights), so
//   spec[f,n] = ( |y_{m=0}|^2 + 2*sum_{m>0} |y_m|^2 ) / (2n+1).
// Only 10 harmonics computed: 6 complex (m>0) + 4 real (m=0, imag==0).
// Packed-f16 datapath otherwise identical to round 3.
//
// ws layout (bytes):
//   [0,     23552) atab2 : h2[16 h][92 e][4] = {(ar0),(ai0),(ar1),(ai1)} replicated pairs
//   [23552, 31744) wT2   : h2[n][f][j][8 cp]
//   [31744, 32768) cw2   : h2[f][8 cp]
//   [32768, 49152) pwT   : f32[(f*4+n)][fo]
//   [49152, 49280) obase : f32[32] = proj_b + proj_w . spec_bias
//   [49280, 49648) edelta: int[92] byte offsets (pre-scaled by 48)
// Entry segments: [0,6)=j0-only, [6,26)=both j, [26,92)=j1-only.
// ---------------------------------------------------------------------------

#define TX 8
#define TY 4
#define TZ 4
#define LXX 12
#define LYY 8
#define LZZ 8
#define NPOS 768
#define CPAD 24           // halves per pos = 48B (16B-aligned, conflict-free stride)
#define POSB 48

#define ATAB2_B 0
#define WT2_B   23552
#define CW2_B   31744
#define PWT_B   32768
#define OB_B    49152
#define ED_B    49280

typedef __half2 h2;
union I4H { int4 v; h2 h[4]; };

__global__ __launch_bounds__(256) void ssh_init(
    const float* __restrict__ w, const float* __restrict__ cw,
    const float* __restrict__ proj_w, const float* __restrict__ spec_bias,
    const float* __restrict__ proj_b, char* __restrict__ wsb)
{
    __shared__ float shr[125][16];
    __shared__ float shi[125][16];
    __shared__ float prof[125][2];
    __shared__ float norms[2][16];
    __shared__ int epos[92];
    const int tid = threadIdx.x;
    const float fourpi = 4.0f * 3.14159265358979323846f;

    for (int p = tid; p < 125; p += 256) {
        int d2 = p % 5, d1 = (p / 5) % 5, d0 = p / 25;
        float xc = (float)(d1 - 2), yc = (float)(d0 - 2), zc = (float)(d2 - 2);
        float r2 = xc*xc + yc*yc + zc*zc;
        float r  = sqrtf(r2);
        float phi = atan2f(yc, xc);
        float ct = (r > 0.f) ? (zc / r) : 0.f;
        float st = sqrtf(fmaxf(0.f, 1.f - ct*ct));
        float c1 = cosf(phi), s1 = sinf(phi);
        float c2 = c1*c1 - s1*s1, s2 = 2.f*s1*c1;
        float c3 = c2*c1 - s2*s1, s3 = s2*c1 + c2*s1;
        float P10 = ct,              P11 = -st;
        float P20 = 0.5f*(3.f*ct*ct - 1.f), P21 = -3.f*ct*st, P22 = 3.f*st*st;
        float P30 = 0.5f*(5.f*ct*ct*ct - 3.f*ct);
        float P31 = -1.5f*(5.f*ct*ct - 1.f)*st;
        float P32 = 15.f*ct*st*st;
        float P33 = -15.f*st*st*st;
        float N00 = sqrtf(1.f/fourpi);
        float N10 = sqrtf(3.f/fourpi);
        float N11 = sqrtf(3.f/fourpi * 0.5f);
        float N20 = sqrtf(5.f/fourpi);
        float N21 = sqrtf(5.f/fourpi / 6.f);
        float N22 = sqrtf(5.f/fourpi / 24.f);
        float N30 = sqrtf(7.f/fourpi);
        float N31 = sqrtf(7.f/fourpi / 12.f);
        float N32 = sqrtf(7.f/fourpi / 120.f);
        float N33 = sqrtf(7.f/fourpi / 720.f);
        float b;
        shr[p][0] = N00;               shi[p][0] = 0.f;
        shr[p][2] = N10*P10;           shi[p][2] = 0.f;
        b = N11*P11;
        shr[p][3] =  b*c1;             shi[p][3] =  b*s1;
        shr[p][1] = -b*c1;             shi[p][1] =  b*s1;
        shr[p][6] = N20*P20;           shi[p][6] = 0.f;
        b = N21*P21;
        shr[p][7] =  b*c1;             shi[p][7] =  b*s1;
        shr[p][5] = -b*c1;             shi[p][5] =  b*s1;
        b = N22*P22;
        shr[p][8] =  b*c2;             shi[p][8] =  b*s2;
        shr[p][4] =  b*c2;             shi[p][4] = -b*s2;
        shr[p][12] = N30*P30;          shi[p][12] = 0.f;
        b = N31*P31;
        shr[p][13] =  b*c1;            shi[p][13] =  b*s1;
        shr[p][11] = -b*c1;            shi[p][11] =  b*s1;
        b = N32*P32;
        shr[p][14] =  b*c2;            shi[p][14] =  b*s2;
        shr[p][10] =  b*c2;            shi[p][10] = -b*s2;
        b = N33*P33;
        shr[p][15] =  b*c3;            shi[p][15] =  b*s3;
        shr[p][9]  = -b*c3;            shi[p][9]  =  b*s3;
        prof[p][0] = fmaxf(0.f, 1.f - fabsf(r - 1.f));
        prof[p][1] = fmaxf(0.f, 1.f - fabsf(r - 2.f));
    }
    __syncthreads();

    if (tid < 32) {
        int j = tid >> 4, h = tid & 15;
        float acc = 0.f;
        for (int p = 0; p < 125; ++p) {
            float pr = prof[p][j];
            acc += pr*pr*(shr[p][h]*shr[p][h] + shi[p][h]*shi[p][h]);
        }
        float nn = sqrtf(acc);
        norms[j][h] = (nn > 0.f) ? nn : 1.f;
    }
    // entry ordering via rank (cls0 base 0, cls1 base 6, cls2 base 26)
    if (tid < 125) {
        int p = tid;
        int d2 = p % 5, d1 = (p / 5) % 5, d0 = p / 25;
        int ix = d1 - 2, iy = d0 - 2, iz = d2 - 2;
        int r2i = ix*ix + iy*iy + iz*iz;
        int cls = (r2i == 1) ? 0 : (r2i == 2 || r2i == 3) ? 1
                : (r2i == 4 || r2i == 5 || r2i == 6 || r2i == 8) ? 2 : -1;
        if (cls >= 0) {
            int rank = (cls == 0) ? 0 : (cls == 1) ? 6 : 26;
            for (int q = 0; q < p; ++q) {
                int e2 = q % 5, e1 = (q / 5) % 5, e0 = q / 25;
                int jx = e1 - 2, jy = e0 - 2, jz = e2 - 2;
                int s2i = jx*jx + jy*jy + jz*jz;
                int c2i = (s2i == 1) ? 0 : (s2i == 2 || s2i == 3) ? 1
                       : (s2i == 4 || s2i == 5 || s2i == 6 || s2i == 8) ? 2 : -1;
                rank += (c2i == cls) ? 1 : 0;
            }
            epos[rank] = p;
            ((int*)(wsb + ED_B))[rank] = (d0*(LYY*LXX) + d1*LXX + d2) * POSB;
        }
    }
    __syncthreads();

    h2* at2 = (h2*)(wsb + ATAB2_B);
    for (int t = tid; t < 92*16; t += 256) {
        int e = t >> 4, h = t & 15;
        int p = epos[e];
        float c0 = prof[p][0] / norms[0][h];
        float c1v = prof[p][1] / norms[1][h];
        at2[(h*92+e)*4 + 0] = __float2half2_rn(c0*shr[p][h]);
        at2[(h*92+e)*4 + 1] = __float2half2_rn(c0*shi[p][h]);
        at2[(h*92+e)*4 + 2] = __float2half2_rn(c1v*shr[p][h]);
        at2[(h*92+e)*4 + 3] = __float2half2_rn(c1v*shi[p][h]);
    }
    // wT2: h2 index = n*512 + f*16 + j*8 + cp
    h2* wt2h = (h2*)(wsb + WT2_B);
    for (int t = tid; t < 2048; t += 256) {
        int n = t >> 9, f = (t >> 4) & 31, j = (t >> 3) & 1, cp = t & 7;
        float a = w[((2*cp*32 + f)*2 + j)*4 + n];
        float b = w[(((2*cp+1)*32 + f)*2 + j)*4 + n];
        wt2h[t] = __halves2half2(__float2half(a), __float2half(b));
    }
    // cw2: h2 index = f*8 + cp
    h2* cw2h = (h2*)(wsb + CW2_B);
    for (int t = tid; t < 256; t += 256) {
        int f = t >> 3, cp = t & 7;
        cw2h[t] = __halves2half2(__float2half(cw[f*16 + 2*cp]),
                                 __float2half(cw[f*16 + 2*cp + 1]));
    }
    // pwT f32 [(f*4+n)][fo]
    float* pwT = (float*)(wsb + PWT_B);
    for (int t = tid; t < 4096; t += 256) {
        int i = t >> 5, fo = t & 31;
        pwT[t] = proj_w[fo*128 + i];
    }
    if (tid < 32) {
        float acc = proj_b[tid];
        for (int i = 0; i < 128; ++i) acc += proj_w[tid*128 + i] * spec_bias[i];
        ((float*)(wsb + OB_B))[tid] = acc;
    }
}

// ---------------- conv passes --------------------------------------------
// complex z rows: [0]=r_j0, [1]=i_j0, [2]=r_j1, [3]=i_j1
// conv2c: two complex harmonics A,B -> zA, zB

__device__ __forceinline__ void conv2c(const __half* __restrict__ ldsh, int baseb,
    const int4* __restrict__ aA, const int4* __restrict__ aB,
    const int* __restrict__ ed, h2 (&zA)[4][8], h2 (&zB)[4][8])
{
#pragma unroll
    for (int r = 0; r < 4; ++r)
#pragma unroll
        for (int q = 0; q < 8; ++q) { zA[r][q] = __float2half2_rn(0.f); zB[r][q] = __float2half2_rn(0.f); }

#pragma unroll 2
    for (int e = 0; e < 6; ++e) {           // j0 only
        I4H ca, cb_, x0, x1;
        ca.v = aA[e]; cb_.v = aB[e];
        const int4* p = (const int4*)((const char*)ldsh + baseb + ed[e]);
        x0.v = p[0]; x1.v = p[1];
#pragma unroll
        for (int q = 0; q < 4; ++q) {
            zA[0][q]   = __hfma2(ca.h[0],  x0.h[q], zA[0][q]);
            zA[1][q]   = __hfma2(ca.h[1],  x0.h[q], zA[1][q]);
            zB[0][q]   = __hfma2(cb_.h[0], x0.h[q], zB[0][q]);
            zB[1][q]   = __hfma2(cb_.h[1], x0.h[q], zB[1][q]);
            zA[0][q+4] = __hfma2(ca.h[0],  x1.h[q], zA[0][q+4]);
            zA[1][q+4] = __hfma2(ca.h[1],  x1.h[q], zA[1][q+4]);
            zB[0][q+4] = __hfma2(cb_.h[0], x1.h[q], zB[0][q+4]);
            zB[1][q+4] = __hfma2(cb_.h[1], x1.h[q], zB[1][q+4]);
        }
    }
#pragma unroll 2
    for (int e = 6; e < 26; ++e) {          // both j
        I4H ca, cb_, x0, x1;
        ca.v = aA[e]; cb_.v = aB[e];
        const int4* p = (const int4*)((const char*)ldsh + baseb + ed[e]);
        x0.v = p[0]; x1.v = p[1];
#pragma unroll
        for (int q = 0; q < 4; ++q) {
            zA[0][q]   = __hfma2(ca.h[0],  x0.h[q], zA[0][q]);
            zA[1][q]   = __hfma2(ca.h[1],  x0.h[q], zA[1][q]);
            zA[2][q]   = __hfma2(ca.h[2],  x0.h[q], zA[2][q]);
            zA[3][q]   = __hfma2(ca.h[3],  x0.h[q], zA[3][q]);
            zB[0][q]   = __hfma2(cb_.h[0], x0.h[q], zB[0][q]);
            zB[1][q]   = __hfma2(cb_.h[1], x0.h[q], zB[1][q]);
            zB[2][q]   = __hfma2(cb_.h[2], x0.h[q], zB[2][q]);
            zB[3][q]   = __hfma2(cb_.h[3], x0.h[q], zB[3][q]);
            zA[0][q+4] = __hfma2(ca.h[0],  x1.h[q], zA[0][q+4]);
            zA[1][q+4] = __hfma2(ca.h[1],  x1.h[q], zA[1][q+4]);
            zA[2][q+4] = __hfma2(ca.h[2],  x1.h[q], zA[2][q+4]);
            zA[3][q+4] = __hfma2(ca.h[3],  x1.h[q], zA[3][q+4]);
            zB[0][q+4] = __hfma2(cb_.h[0], x1.h[q], zB[0][q+4]);
            zB[1][q+4] = __hfma2(cb_.h[1], x1.h[q], zB[1][q+4]);
            zB[2][q+4] = __hfma2(cb_.h[2], x1.h[q], zB[2][q+4]);
            zB[3][q+4] = __hfma2(cb_.h[3], x1.h[q], zB[3][q+4]);
        }
    }
#pragma unroll 2
    for (int e = 26; e < 92; ++e) {         // j1 only
        I4H ca, cb_, x0, x1;
        ca.v = aA[e]; cb_.v = aB[e];
        const int4* p = (const int4*)((const char*)ldsh + baseb + ed[e]);
        x0.v = p[0]; x1.v = p[1];
#pragma unroll
        for (int q = 0; q < 4; ++q) {
            zA[2][q]   = __hfma2(ca.h[2],  x0.h[q], zA[2][q]);
            zA[3][q]   = __hfma2(ca.h[3],  x0.h[q], zA[3][q]);
            zB[2][q]   = __hfma2(cb_.h[2], x0.h[q], zB[2][q]);
            zB[3][q]   = __hfma2(cb_.h[3], x0.h[q], zB[3][q]);
            zA[2][q+4] = __hfma2(ca.h[2],  x1.h[q], zA[2][q+4]);
            zA[3][q+4] = __hfma2(ca.h[3],  x1.h[q], zA[3][q+4]);
            zB[2][q+4] = __hfma2(cb_.h[2], x1.h[q], zB[2][q+4]);
            zB[3][q+4] = __hfma2(cb_.h[3], x1.h[q], zB[3][q+4]);
        }
    }
}

__device__ __forceinline__ void conv1c(const __half* __restrict__ ldsh, int baseb,
    const int4* __restrict__ aA, const int* __restrict__ ed, h2 (&zA)[4][8])
{
#pragma unroll
    for (int r = 0; r < 4; ++r)
#pragma unroll
        for (int q = 0; q < 8; ++q) zA[r][q] = __float2half2_rn(0.f);

#pragma unroll 2
    for (int e = 0; e < 6; ++e) {
        I4H ca, x0, x1;
        ca.v = aA[e];
        const int4* p = (const int4*)((const char*)ldsh + baseb + ed[e]);
        x0.v = p[0]; x1.v = p[1];
#pragma unroll
        for (int q = 0; q < 4; ++q) {
            zA[0][q]   = __hfma2(ca.h[0], x0.h[q], zA[0][q]);
            zA[1][q]   = __hfma2(ca.h[1], x0.h[q], zA[1][q]);
            zA[0][q+4] = __hfma2(ca.h[0], x1.h[q], zA[0][q+4]);
            zA[1][q+4] = __hfma2(ca.h[1], x1.h[q], zA[1][q+4]);
        }
    }
#pragma unroll 2
    for (int e = 6; e < 26; ++e) {
        I4H ca, x0, x1;
        ca.v = aA[e];
        const int4* p = (const int4*)((const char*)ldsh + baseb + ed[e]);
        x0.v = p[0]; x1.v = p[1];
#pragma unroll
        for (int q = 0; q < 4; ++q) {
            zA[0][q]   = __hfma2(ca.h[0], x0.h[q], zA[0][q]);
            zA[1][q]   = __hfma2(ca.h[1], x0.h[q], zA[1][q]);
            zA[2][q]   = __hfma2(ca.h[2], x0.h[q], zA[2][q]);
            zA[3][q]   = __hfma2(ca.h[3], x0.h[q], zA[3][q]);
            zA[0][q+4] = __hfma2(ca.h[0], x1.h[q], zA[0][q+4]);
            zA[1][q+4] = __hfma2(ca.h[1], x1.h[q], zA[1][q+4]);
            zA[2][q+4] = __hfma2(ca.h[2], x1.h[q], zA[2][q+4]);
            zA[3][q+4] = __hfma2(ca.h[3], x1.h[q], zA[3][q+4]);
        }
    }
#pragma unroll 2
    for (int e = 26; e < 92; ++e) {
        I4H ca, x0, x1;
        ca.v = aA[e];
        const int4* p = (const int4*)((const char*)ldsh + baseb + ed[e]);
        x0.v = p[0]; x1.v = p[1];
#pragma unroll
        for (int q = 0; q < 4; ++q) {
            zA[2][q]   = __hfma2(ca.h[2], x0.h[q], zA[2][q]);
            zA[3][q]   = __hfma2(ca.h[3], x0.h[q], zA[3][q]);
            zA[2][q+4] = __hfma2(ca.h[2], x1.h[q], zA[2][q+4]);
            zA[3][q+4] = __hfma2(ca.h[3], x1.h[q], zA[3][q+4]);
        }
    }
}

// two REAL harmonics A,B (m=0, imag==0).  z rows: [0]=A_j0, [1]=A_j1, [2]=B_j0, [3]=B_j1
__device__ __forceinline__ void conv2r(const __half* __restrict__ ldsh, int baseb,
    const int4* __restrict__ aA, const int4* __restrict__ aB,
    const int* __restrict__ ed, h2 (&z)[4][8])
{
#pragma unroll
    for (int r = 0; r < 4; ++r)
#pragma unroll
        for (int q = 0; q < 8; ++q) z[r][q] = __float2half2_rn(0.f);

#pragma unroll 2
    for (int e = 0; e < 6; ++e) {           // j0 only
        I4H ca, cb_, x0, x1;
        ca.v = aA[e]; cb_.v = aB[e];
        const int4* p = (const int4*)((const char*)ldsh + baseb + ed[e]);
        x0.v = p[0]; x1.v = p[1];
#pragma unroll
        for (int q = 0; q < 4; ++q) {
            z[0][q]   = __hfma2(ca.h[0],  x0.h[q], z[0][q]);
            z[2][q]   = __hfma2(cb_.h[0], x0.h[q], z[2][q]);
            z[0][q+4] = __hfma2(ca.h[0],  x1.h[q], z[0][q+4]);
            z[2][q+4] = __hfma2(cb_.h[0], x1.h[q], z[2][q+4]);
        }
    }
#pragma unroll 2
    for (int e = 6; e < 26; ++e) {          // both j
        I4H ca, cb_, x0, x1;
        ca.v = aA[e]; cb_.v = aB[e];
        const int4* p = (const int4*)((const char*)ldsh + baseb + ed[e]);
        x0.v = p[0]; x1.v = p[1];
#pragma unroll
        for (int q = 0; q < 4; ++q) {
            z[0][q]   = __hfma2(ca.h[0],  x0.h[q], z[0][q]);
            z[1][q]   = __hfma2(ca.h[2],  x0.h[q], z[1][q]);
            z[2][q]   = __hfma2(cb_.h[0], x0.h[q], z[2][q]);
            z[3][q]   = __hfma2(cb_.h[2], x0.h[q], z[3][q]);
            z[0][q+4] = __hfma2(ca.h[0],  x1.h[q], z[0][q+4]);
            z[1][q+4] = __hfma2(ca.h[2],  x1.h[q], z[1][q+4]);
            z[2][q+4] = __hfma2(cb_.h[0], x1.h[q], z[2][q+4]);
            z[3][q+4] = __hfma2(cb_.h[2], x1.h[q], z[3][q+4]);
        }
    }
#pragma unroll 2
    for (int e = 26; e < 92; ++e) {         // j1 only
        I4H ca, cb_, x0, x1;
        ca.v = aA[e]; cb_.v = aB[e];
        const int4* p = (const int4*)((const char*)ldsh + baseb + ed[e]);
        x0.v = p[0]; x1.v = p[1];
#pragma unroll
        for (int q = 0; q < 4; ++q) {
            z[1][q]   = __hfma2(ca.h[2],  x0.h[q], z[1][q]);
            z[3][q]   = __hfma2(cb_.h[2], x0.h[q], z[3][q]);
            z[1][q+4] = __hfma2(ca.h[2],  x1.h[q], z[1][q+4]);
            z[3][q+4] = __hfma2(cb_.h[2], x1.h[q], z[3][q+4]);
        }
    }
}

// ---------------- mixing + spectrum + fused projection --------------------

// complex harmonic (m>0): weight 2/(2n+1)
template<int N>
__device__ __forceinline__ void mixc(const h2 (&z)[4][8],
    const int4* __restrict__ wt2n, const float* __restrict__ pwT, float2 (&outa)[16])
{
    const float W = 2.f / (float)(2*N + 1);
#pragma unroll 2
    for (int f = 0; f < 32; ++f) {
        I4H w00, w01, w10, w11;
        w00.v = wt2n[f*4+0]; w01.v = wt2n[f*4+1];
        w10.v = wt2n[f*4+2]; w11.v = wt2n[f*4+3];
        h2 yr = __float2half2_rn(0.f), yi = __float2half2_rn(0.f);
#pragma unroll
        for (int q = 0; q < 4; ++q) {
            yr = __hfma2(w00.h[q], z[0][q],   yr);
            yr = __hfma2(w01.h[q], z[0][q+4], yr);
            yr = __hfma2(w10.h[q], z[2][q],   yr);
            yr = __hfma2(w11.h[q], z[2][q+4], yr);
            yi = __hfma2(w00.h[q], z[1][q],   yi);
            yi = __hfma2(w01.h[q], z[1][q+4], yi);
            yi = __hfma2(w10.h[q], z[3][q],   yi);
            yi = __hfma2(w11.h[q], z[3][q+4], yi);
        }
        float yrf = __low2float(yr) + __high2float(yr);
        float yif = __low2float(yi) + __high2float(yi);
        float s = (yrf*yrf + yif*yif) * W;
        const float2* pw2 = (const float2*)(pwT + (f*4 + N)*32);
#pragma unroll
        for (int k = 0; k < 16; ++k) {
            float2 t = pw2[k];
            outa[k].x = fmaf(t.x, s, outa[k].x);
            outa[k].y = fmaf(t.y, s, outa[k].y);
        }
    }
}

// real harmonic (m=0): weight 1/(2n+1); rows R (j0) and R+1 (j1)
template<int R, int N, bool CENTRAL>
__device__ __forceinline__ void mixr(const h2 (&z)[4][8],
    const int4* __restrict__ wt2n, const int4* __restrict__ cw2,
    const float* __restrict__ cbp, const __half* __restrict__ ldsh, int baseb,
    const float* __restrict__ pwT, float2 (&outa)[16])
{
    const float W = 1.f / (float)(2*N + 1);
    h2 xc[8];
    if (CENTRAL) {
        const int4* pc = (const int4*)((const char*)ldsh + baseb + 218*POSB);
        I4H xc0, xc1; xc0.v = pc[0]; xc1.v = pc[1];
#pragma unroll
        for (int q = 0; q < 4; ++q) { xc[q] = xc0.h[q]; xc[q+4] = xc1.h[q]; }
    }
#pragma unroll 2
    for (int f = 0; f < 32; ++f) {
        I4H w00, w01, w10, w11;
        w00.v = wt2n[f*4+0]; w01.v = wt2n[f*4+1];
        w10.v = wt2n[f*4+2]; w11.v = wt2n[f*4+3];
        h2 yr = __float2half2_rn(0.f);
#pragma unroll
        for (int q = 0; q < 4; ++q) {
            yr = __hfma2(w00.h[q], z[R][q],     yr);
            yr = __hfma2(w01.h[q], z[R][q+4],   yr);
            yr = __hfma2(w10.h[q], z[R+1][q],   yr);
            yr = __hfma2(w11.h[q], z[R+1][q+4], yr);
        }
        float yrf = __low2float(yr) + __high2float(yr);
        if (CENTRAL) {
            I4H c0, c1; c0.v = cw2[f*2]; c1.v = cw2[f*2+1];
            h2 acc = __float2half2_rn(0.f);
#pragma unroll
            for (int q = 0; q < 4; ++q) {
                acc = __hfma2(c0.h[q], xc[q],   acc);
                acc = __hfma2(c1.h[q], xc[q+4], acc);
            }
            yrf += cbp[f] + __low2float(acc) + __high2float(acc);
        }
        float s = yrf*yrf * W;
        const float2* pw2 = (const float2*)(pwT + (f*4 + N)*32);
#pragma unroll
        for (int k = 0; k < 16; ++k) {
            float2 t = pw2[k];
            outa[k].x = fmaf(t.x, s, outa[k].x);
            outa[k].y = fmaf(t.y, s, outa[k].y);
        }
    }
}

__global__ __launch_bounds__(256, 3) void ssh_main(
    const float* __restrict__ x, const float* __restrict__ cb,
    const char* __restrict__ wsb, float* __restrict__ out)
{
    __shared__ __align__(16) __half ldsh[NPOS * CPAD];   // 36864 B
    const int tid = threadIdx.x;
    const int x0 = blockIdx.x * TX, y0 = blockIdx.y * TY, z0 = blockIdx.z * TZ;

    // stage x -> f16 LDS, channel-fastest, 2 channels per write (b32)
    for (int i = tid; i < NPOS * 8; i += 256) {
        int cp = i / NPOS;
        int pos = i - cp * NPOS;
        int lx = pos % LXX; int t1 = pos / LXX;
        int ly = t1 % LYY;  int lz = t1 / LYY;
        int gx = x0 + lx - 2, gy = y0 + ly - 2, gz = z0 + lz - 2;
        h2 hv = __float2half2_rn(0.f);
        if ((unsigned)gx < 48u && (unsigned)gy < 48u && (unsigned)gz < 48u) {
            int gi = ((2*cp*48 + gz)*48 + gy)*48 + gx;
            hv = __floats2half2_rn(x[gi], x[gi + 48*48*48]);
        }
        *(h2*)(ldsh + pos*CPAD + 2*cp) = hv;
    }
    __syncthreads();

    const int hf  = tid >> 7;
    const int vid = tid & 127;
    const int tx = vid & 7, ty = (vid >> 3) & 3, tz = vid >> 5;
    const int baseb = (tz*(LYY*LXX) + ty*LXX + tx) * POSB;

    const int4* __restrict__ atab = (const int4*)(wsb + ATAB2_B);
    const int4* __restrict__ wt2  = (const int4*)(wsb + WT2_B);
    const int4* __restrict__ cw2  = (const int4*)(wsb + CW2_B);
    const float* __restrict__ pwT = (const float*)(wsb + PWT_B);
    const float* __restrict__ obase = (const float*)(wsb + OB_B);
    const int* __restrict__ ed    = (const int*)(wsb + ED_B);

    float2 outa[16];
#pragma unroll
    for (int k = 0; k < 16; ++k) outa[k] = make_float2(0.f, 0.f);

    h2 zA[4][8], zB[4][8];
    if (hf == 0) {
        // n=3: (3,1)=h13, (3,2)=h14, (3,3)=h15, (3,0)=h12; n=0: (0,0)=h0 + central
        conv2c(ldsh, baseb, atab + 13*92, atab + 14*92, ed, zA, zB);
        mixc<3>(zA, wt2 + 3*128, pwT, outa);
        mixc<3>(zB, wt2 + 3*128, pwT, outa);
        conv1c(ldsh, baseb, atab + 15*92, ed, zA);
        mixc<3>(zA, wt2 + 3*128, pwT, outa);
        conv2r(ldsh, baseb, atab + 12*92, atab + 0*92, ed, zB);
        mixr<0,3,false>(zB, wt2 + 3*128, cw2, cb, ldsh, baseb, pwT, outa);
        mixr<2,0,true >(zB, wt2 + 0*128, cw2, cb, ldsh, baseb, pwT, outa);
    } else {
        // n=2: (2,1)=h7, (2,2)=h8, (2,0)=h6; n=1: (1,1)=h3, (1,0)=h2
        conv2c(ldsh, baseb, atab + 7*92, atab + 8*92, ed, zA, zB);
        mixc<2>(zA, wt2 + 2*128, pwT, outa);
        mixc<2>(zB, wt2 + 2*128, pwT, outa);
        conv2r(ldsh, baseb, atab + 6*92, atab + 2*92, ed, zA);
        mixr<0,2,false>(zA, wt2 + 2*128, cw2, cb, ldsh, baseb, pwT, outa);
        conv1c(ldsh, baseb, atab + 3*92, ed, zB);
        mixc<1>(zB, wt2 + 1*128, pwT, outa);
        mixr<2,1,false>(zA, wt2 + 1*128, cw2, cb, ldsh, baseb, pwT, outa);
    }

    // merge halves through LDS (x-tile is dead now); stride 33 avoids conflicts
    __syncthreads();
    float* lmerge = (float*)ldsh;
    if (hf == 1) {
#pragma unroll
        for (int k = 0; k < 16; ++k) {
            lmerge[vid*33 + 2*k]     = outa[k].x;
            lmerge[vid*33 + 2*k + 1] = outa[k].y;
        }
    }
    __syncthreads();
    if (hf == 0) {
        const int gz = z0 + tz, gy = y0 + ty, gx = x0 + tx;
#pragma unroll
        for (int k = 0; k < 16; ++k) {
            float v0 = obase[2*k]   + outa[k].x + lmerge[vid*33 + 2*k];
            float v1 = obase[2*k+1] + outa[k].y + lmerge[vid*33 + 2*k + 1];
            out[(((2*k)*48   + gz)*48 + gy)*48 + gx] = fmaxf(v0, 0.f);
            out[(((2*k+1)*48 + gz)*48 + gy)*48 + gx] = fmaxf(v1, 0.f);
        }
    }
}

extern "C" void kernel_launch(void* const* d_in, const int* in_sizes, int n_in,
                              void* d_out, int out_size, void* d_ws, size_t ws_size,
                              hipStream_t stream) {
    const float* x  = (const float*)d_in[0];
    const float* w  = (const float*)d_in[1];
    const float* cw = (const float*)d_in[2];
    const float* cb = (const float*)d_in[3];
    const float* sb = (const float*)d_in[4];
    const float* pw = (const float*)d_in[5];
    const float* pb = (const float*)d_in[6];
    float* out = (float*)d_out;
    char* wsb = (char*)d_ws;

    ssh_init<<<dim3(1), dim3(256), 0, stream>>>(w, cw, pw, sb, pb, wsb);
    ssh_main<<<dim3(48/TX, 48/TY, 48/TZ), dim3(256), 0, stream>>>(x, cb, wsb, out);
}